// Round 8
// baseline (1087.055 us; speedup 1.0000x reference)
//
#include <hip/hip_runtime.h>

#define NNB 32

__device__ __forceinline__ float sigmoid_fast(float x) {
    float e = __expf(-x);
#if __has_builtin(__builtin_amdgcn_rcpf)
    return __builtin_amdgcn_rcpf(1.0f + e);
#else
    return __fdividef(1.0f, 1.0f + e);
#endif
}

__device__ __forceinline__ float wave_reduce_sum(float t) {
#pragma unroll
    for (int off = 32; off >= 1; off >>= 1)
        t += __shfl_xor(t, off, 64);
    return t;
}

__global__ __launch_bounds__(256, 2)
void jet_eff_kernel(const float* __restrict__ jet_inp,
                    const float* __restrict__ neigh_inp,
                    const float* __restrict__ jW1, const float* __restrict__ jb1,
                    const float* __restrict__ jW2, const float* __restrict__ jb2,
                    const float* __restrict__ jW3, const float* __restrict__ jb3,
                    const float* __restrict__ nW1, const float* __restrict__ nb1,
                    const float* __restrict__ nW2, const float* __restrict__ nb2,
                    const float* __restrict__ nW3, const float* __restrict__ nb3,
                    float* __restrict__ out, int B)
{
    const int lane = threadIdx.x & 63;
    const int wid  = threadIdx.x >> 6;

    // Per-lane weight COLUMNS resident in VGPRs (lane j holds column j).
    // W[k][j] = W[k*64 + j]; loads are coalesced per-k (64 lanes x 4B).
    float w_jW1[16], w_jW2[64], w_nW1[32], w_nW2[64];
#pragma unroll
    for (int k = 0; k < 16; ++k) w_jW1[k] = jW1[k*64 + lane];
#pragma unroll
    for (int k = 0; k < 64; ++k) w_jW2[k] = jW2[k*64 + lane];
#pragma unroll
    for (int k = 0; k < 32; ++k) w_nW1[k] = nW1[k*64 + lane];
#pragma unroll
    for (int k = 0; k < 64; ++k) w_nW2[k] = nW2[k*64 + lane];
    const float w_jw3 = jW3[lane];
    const float w_nw3 = nW3[lane];
    const float b_j1 = jb1[lane], b_j2 = jb2[lane];
    const float b_n1 = nb1[lane], b_n2 = nb2[lane];
    const float b_j3 = jb3[0],    b_n3 = nb3[0];

    // Per-wave private staging; all reads below are same-address broadcasts
    // (conflict-free) or the 1-per-lane h1 write.
    __shared__ float  s_jet[4][16];
    __shared__ float4 s_nb[4][128];   // 32 neighbors * 16 feats
    __shared__ float  s_h1[4][64];

    const int gwave = blockIdx.x * 4 + wid;
    const int nwave = gridDim.x * 4;

    for (int jet = gwave; jet < B; jet += nwave) {
        // ---- stage inputs (coalesced) ----
        if (lane < 16) s_jet[wid][lane] = jet_inp[(size_t)jet*16 + lane];
        const float4* np4 = (const float4*)(neigh_inp + (size_t)jet*(NNB*16));
        s_nb[wid][lane]      = np4[lane];
        s_nb[wid][64 + lane] = np4[64 + lane];
        asm volatile("" ::: "memory");   // same-wave LDS is in-order; pin compiler

        // ---- jet MLP ----
        float a0 = b_j1, a1 = 0.f;
#pragma unroll
        for (int k = 0; k < 16; k += 2) {
            a0 = fmaf(s_jet[wid][k],   w_jW1[k],   a0);
            a1 = fmaf(s_jet[wid][k+1], w_jW1[k+1], a1);
        }
        float hj = fmaxf(a0 + a1, 0.f);
        s_h1[wid][lane] = hj;
        asm volatile("" ::: "memory");
        const float4* h1v = (const float4*)s_h1[wid];
        float c0 = b_j2, c1 = 0.f;
#pragma unroll
        for (int k4 = 0; k4 < 16; ++k4) {
            float4 h = h1v[k4];
            c0 = fmaf(h.x, w_jW2[4*k4+0], c0);
            c1 = fmaf(h.y, w_jW2[4*k4+1], c1);
            c0 = fmaf(h.z, w_jW2[4*k4+2], c0);
            c1 = fmaf(h.w, w_jW2[4*k4+3], c1);
        }
        float h2j = fmaxf(c0 + c1, 0.f);
        float tj = wave_reduce_sum(h2j * w_jw3);
        float prod = sigmoid_fast(tj + b_j3);   // jet_eff; product accumulates on top

        // ---- hoisted jet-feature part of neighbor L1 (shared by all 32 nbrs) ----
        float p0 = b_n1, p1 = 0.f;
#pragma unroll
        for (int k = 0; k < 16; k += 2) {
            p0 = fmaf(s_jet[wid][k],   w_nW1[k],   p0);
            p1 = fmaf(s_jet[wid][k+1], w_nW1[k+1], p1);
        }
        const float pre = p0 + p1;

        // prologue: L1 for neighbor 0
        float h1cur;
        {
            const float4* zb = &s_nb[wid][0];
            float q0 = pre, q1 = 0.f;
#pragma unroll
            for (int k4 = 0; k4 < 4; ++k4) {
                float4 z = zb[k4];
                q0 = fmaf(z.x, w_nW1[16+4*k4+0], q0);
                q1 = fmaf(z.y, w_nW1[16+4*k4+1], q1);
                q0 = fmaf(z.z, w_nW1[16+4*k4+2], q0);
                q1 = fmaf(z.w, w_nW1[16+4*k4+3], q1);
            }
            h1cur = fmaxf(q0 + q1, 0.f);
        }

        for (int n = 0; n < NNB; ++n) {
            // broadcast h1 across the wave via per-wave LDS (in-order pipe)
            s_h1[wid][lane] = h1cur;
            asm volatile("" ::: "memory");
            float d0 = b_n2, d1 = 0.f;
#pragma unroll
            for (int k4 = 0; k4 < 16; ++k4) {
                float4 h = h1v[k4];
                d0 = fmaf(h.x, w_nW2[4*k4+0], d0);
                d1 = fmaf(h.y, w_nW2[4*k4+1], d1);
                d0 = fmaf(h.z, w_nW2[4*k4+2], d0);
                d1 = fmaf(h.w, w_nW2[4*k4+3], d1);
            }
            float h2n = fmaxf(d0 + d1, 0.f);
            float tn = h2n * w_nw3;

            // software-pipeline: next neighbor's L1 overlaps the reduce latency
            if (n + 1 < NNB) {
                const float4* zb = &s_nb[wid][(n+1)*4];
                float q0 = pre, q1 = 0.f;
#pragma unroll
                for (int k4 = 0; k4 < 4; ++k4) {
                    float4 z = zb[k4];
                    q0 = fmaf(z.x, w_nW1[16+4*k4+0], q0);
                    q1 = fmaf(z.y, w_nW1[16+4*k4+1], q1);
                    q0 = fmaf(z.z, w_nW1[16+4*k4+2], q0);
                    q1 = fmaf(z.w, w_nW1[16+4*k4+3], q1);
                }
                h1cur = fmaxf(q0 + q1, 0.f);
            }

            tn = wave_reduce_sum(tn);
            prod *= sigmoid_fast(tn + b_n3);
        }

        if (lane == 0) out[jet] = prod;
    }
}

extern "C" void kernel_launch(void* const* d_in, const int* in_sizes, int n_in,
                              void* d_out, int out_size, void* d_ws, size_t ws_size,
                              hipStream_t stream) {
    const float* jet_inp = (const float*)d_in[0];
    const float* neigh   = (const float*)d_in[1];
    const float* jW1 = (const float*)d_in[2];
    const float* jb1 = (const float*)d_in[3];
    const float* jW2 = (const float*)d_in[4];
    const float* jb2 = (const float*)d_in[5];
    const float* jW3 = (const float*)d_in[6];
    const float* jb3 = (const float*)d_in[7];
    const float* nW1 = (const float*)d_in[8];
    const float* nb1 = (const float*)d_in[9];
    const float* nW2 = (const float*)d_in[10];
    const float* nb2 = (const float*)d_in[11];
    const float* nW3 = (const float*)d_in[12];
    const float* nb3 = (const float*)d_in[13];
    float* out = (float*)d_out;
    const int B = in_sizes[0] / 16;

    dim3 grid(1024), block(256);
    hipLaunchKernelGGL(jet_eff_kernel, grid, block, 0, stream,
                       jet_inp, neigh, jW1, jb1, jW2, jb2, jW3, jb3,
                       nW1, nb1, nW2, nb2, nW3, nb3, out, B);
}

// Round 9
// 767.088 us; speedup vs baseline: 1.4171x; 1.4171x over previous
//
#include <hip/hip_runtime.h>

#define NNB 32

__device__ __forceinline__ float sigmoid_fast(float x) {
    float e = __expf(-x);
    return __fdividef(1.0f, 1.0f + e);
}

__device__ __forceinline__ float wave_reduce_sum(float t) {
#pragma unroll
    for (int off = 32; off >= 1; off >>= 1)
        t += __shfl_xor(t, off, 64);
    return t;
}

// ---------------- K1: jet MLP -> sigmoid -> ws[jet] ----------------
// Reuses the measured-correct R8 pattern: wave = 1 jet, lane = hidden unit,
// jW columns resident in VGPRs, h1 broadcast via per-wave LDS.
__global__ __launch_bounds__(256, 2)
void jet_mlp_kernel(const float* __restrict__ jet_inp,
                    const float* __restrict__ jW1, const float* __restrict__ jb1,
                    const float* __restrict__ jW2, const float* __restrict__ jb2,
                    const float* __restrict__ jW3, const float* __restrict__ jb3,
                    float* __restrict__ ws, int B)
{
    const int lane = threadIdx.x & 63;
    const int wid  = threadIdx.x >> 6;
    float w1[16], w2[64];
#pragma unroll
    for (int k = 0; k < 16; ++k) w1[k] = jW1[k*64 + lane];
#pragma unroll
    for (int k = 0; k < 64; ++k) w2[k] = jW2[k*64 + lane];
    const float w3 = jW3[lane], b1 = jb1[lane], b2 = jb2[lane], b3 = jb3[0];

    __shared__ float s_jet[4][16];
    __shared__ float s_h1[4][64];

    const int gw = blockIdx.x * 4 + wid;
    const int nw = gridDim.x * 4;
    for (int jet = gw; jet < B; jet += nw) {
        if (lane < 16) s_jet[wid][lane] = jet_inp[(size_t)jet*16 + lane];
        asm volatile("" ::: "memory");
        float a0 = b1, a1 = 0.f;
#pragma unroll
        for (int k = 0; k < 16; k += 2) {
            a0 = fmaf(s_jet[wid][k],   w1[k],   a0);
            a1 = fmaf(s_jet[wid][k+1], w1[k+1], a1);
        }
        s_h1[wid][lane] = fmaxf(a0 + a1, 0.f);
        asm volatile("" ::: "memory");
        const float4* h1v = (const float4*)s_h1[wid];
        float c0 = b2, c1 = 0.f;
#pragma unroll
        for (int k4 = 0; k4 < 16; ++k4) {
            float4 h = h1v[k4];
            c0 = fmaf(h.x, w2[4*k4+0], c0);
            c1 = fmaf(h.y, w2[4*k4+1], c1);
            c0 = fmaf(h.z, w2[4*k4+2], c0);
            c1 = fmaf(h.w, w2[4*k4+3], c1);
        }
        float t = wave_reduce_sum(fmaxf(c0 + c1, 0.f) * w3);
        if (lane == 0) ws[jet] = sigmoid_fast(t + b3);
    }
}

// ---------------- K2: neighbor streams ----------------
// lane = (jet_half, neighbor): 64 lanes = 2 jets x 32 neighbors.
// Each lane computes its neighbor's full MLP in registers (h1[64], static
// indices only). Weights are wave-uniform reads from global (s_load /
// L1-cached). ZERO LDS ops, zero cross-lane ops until the final 5-shuffle
// log-sigmoid reduce per jet pair.
__global__ __launch_bounds__(256, 2)
void neigh_streams_kernel(const float* __restrict__ jet_inp,
                          const float* __restrict__ neigh_inp,
                          const float* __restrict__ nW1, const float* __restrict__ nb1,
                          const float* __restrict__ nW2, const float* __restrict__ nb2,
                          const float* __restrict__ nW3, const float* __restrict__ nb3,
                          const float* __restrict__ jet_eff,
                          float* __restrict__ out, int B)
{
    const int lane = threadIdx.x & 63;
    const int half = lane >> 5;   // 0 = jet A, 1 = jet B
    const int nb   = lane & 31;   // neighbor index
    const int wid  = threadIdx.x >> 6;
    const int gw = blockIdx.x * 4 + wid;
    const int nw = gridDim.x * 4;
    const int npairs = B >> 1;
    const float bias3 = nb3[0];

    for (int pair = gw; pair < npairs; pair += nw) {
        const int jet = pair * 2 + half;

        // ---- per-lane input x[32] = [jet feats 16 | neighbor feats 16] ----
        float x[32];
        {
            const float4* jp = (const float4*)(jet_inp + (size_t)jet * 16);
#pragma unroll
            for (int q = 0; q < 4; ++q) {
                float4 v = jp[q];
                x[4*q+0] = v.x; x[4*q+1] = v.y; x[4*q+2] = v.z; x[4*q+3] = v.w;
            }
            const float4* np = (const float4*)(neigh_inp + (size_t)jet * (NNB*16)
                                               + (size_t)nb * 16);
#pragma unroll
            for (int q = 0; q < 4; ++q) {
                float4 v = np[q];
                x[16+4*q+0] = v.x; x[16+4*q+1] = v.y;
                x[16+4*q+2] = v.z; x[16+4*q+3] = v.w;
            }
        }

        // ---- L1: h1[64] = relu(W1^T x + b1), 16-wide tiles, fully static ----
        float h1[64];
#pragma unroll
        for (int jb = 0; jb < 4; ++jb) {          // MUST fully unroll (static h1 idx)
            float acc[16];
#pragma unroll
            for (int t = 0; t < 16; ++t) acc[t] = nb1[jb*16 + t];
#pragma unroll
            for (int k = 0; k < 32; ++k) {
                const float* wrow = nW1 + k*64 + jb*16;   // wave-uniform
#pragma unroll
                for (int t = 0; t < 16; ++t) acc[t] = fmaf(x[k], wrow[t], acc[t]);
            }
#pragma unroll
            for (int t = 0; t < 16; ++t) h1[jb*16 + t] = fmaxf(acc[t], 0.f);
        }

        // ---- L2 + folded L3: t_n = sum_m w3[m] * relu(W2^T h1 + b2)[m] ----
        float ts0 = 0.f, ts1 = 0.f;
#pragma unroll 1
        for (int mb = 0; mb < 4; ++mb) {          // keep rolled: I-cache
            float acc[16];
#pragma unroll
            for (int t = 0; t < 16; ++t) acc[t] = nb2[mb*16 + t];
#pragma unroll
            for (int k = 0; k < 64; ++k) {        // full unroll: h1[k] static
                const float* wrow = nW2 + k*64 + mb*16;   // wave-uniform
#pragma unroll
                for (int t = 0; t < 16; ++t) acc[t] = fmaf(h1[k], wrow[t], acc[t]);
            }
            const float* w3p = nW3 + mb*16;
#pragma unroll
            for (int t = 0; t < 16; t += 2) {
                ts0 = fmaf(fmaxf(acc[t],   0.f), w3p[t],   ts0);
                ts1 = fmaf(fmaxf(acc[t+1], 0.f), w3p[t+1], ts1);
            }
        }
        const float t_n = ts0 + ts1 + bias3;

        // ---- log-sigmoid, then one reduce per half-wave ----
        float z  = __expf(-t_n);
        float ls = -__logf(1.0f + z);
#pragma unroll
        for (int off = 16; off >= 1; off >>= 1)
            ls += __shfl_xor(ls, off, 64);        // sums within each 32-lane half
        float corr = __expf(ls);

        if (nb == 0) out[jet] = jet_eff[jet] * corr;
    }
}

extern "C" void kernel_launch(void* const* d_in, const int* in_sizes, int n_in,
                              void* d_out, int out_size, void* d_ws, size_t ws_size,
                              hipStream_t stream) {
    const float* jet_inp = (const float*)d_in[0];
    const float* neigh   = (const float*)d_in[1];
    const float* jW1 = (const float*)d_in[2];
    const float* jb1 = (const float*)d_in[3];
    const float* jW2 = (const float*)d_in[4];
    const float* jb2 = (const float*)d_in[5];
    const float* jW3 = (const float*)d_in[6];
    const float* jb3 = (const float*)d_in[7];
    const float* nW1 = (const float*)d_in[8];
    const float* nb1 = (const float*)d_in[9];
    const float* nW2 = (const float*)d_in[10];
    const float* nb2 = (const float*)d_in[11];
    const float* nW3 = (const float*)d_in[12];
    const float* nb3 = (const float*)d_in[13];
    float* out = (float*)d_out;
    float* ws  = (float*)d_ws;
    const int B = in_sizes[0] / 16;

    dim3 block(256);
    hipLaunchKernelGGL(jet_mlp_kernel, dim3(1024), block, 0, stream,
                       jet_inp, jW1, jb1, jW2, jb2, jW3, jb3, ws, B);
    hipLaunchKernelGGL(neigh_streams_kernel, dim3(1024), block, 0, stream,
                       jet_inp, neigh, nW1, nb1, nW2, nb2, nW3, nb3,
                       ws, out, B);
}

// Round 11
// 559.477 us; speedup vs baseline: 1.9430x; 1.3711x over previous
//
#include <hip/hip_runtime.h>

#define NNB 32

__device__ __forceinline__ float sigmoid_fast(float x) {
    return __fdividef(1.0f, 1.0f + __expf(-x));
}

// ---- repetition macros: ALL register-array indices are compile-time
// literals (rule #20: runtime-indexed arrays go to scratch; literal-indexed
// arrays are SROA'd into scalars regardless of unroll heuristics). ----
#define LOAD16(a, s) \
  a[0]=(s)[0];   a[1]=(s)[1];   a[2]=(s)[2];   a[3]=(s)[3]; \
  a[4]=(s)[4];   a[5]=(s)[5];   a[6]=(s)[6];   a[7]=(s)[7]; \
  a[8]=(s)[8];   a[9]=(s)[9];   a[10]=(s)[10]; a[11]=(s)[11]; \
  a[12]=(s)[12]; a[13]=(s)[13]; a[14]=(s)[14]; a[15]=(s)[15];

#define FMA16(a, s, w) \
  a[0]=fmaf((s),(w)[0],a[0]);    a[1]=fmaf((s),(w)[1],a[1]); \
  a[2]=fmaf((s),(w)[2],a[2]);    a[3]=fmaf((s),(w)[3],a[3]); \
  a[4]=fmaf((s),(w)[4],a[4]);    a[5]=fmaf((s),(w)[5],a[5]); \
  a[6]=fmaf((s),(w)[6],a[6]);    a[7]=fmaf((s),(w)[7],a[7]); \
  a[8]=fmaf((s),(w)[8],a[8]);    a[9]=fmaf((s),(w)[9],a[9]); \
  a[10]=fmaf((s),(w)[10],a[10]); a[11]=fmaf((s),(w)[11],a[11]); \
  a[12]=fmaf((s),(w)[12],a[12]); a[13]=fmaf((s),(w)[13],a[13]); \
  a[14]=fmaf((s),(w)[14],a[14]); a[15]=fmaf((s),(w)[15],a[15]);

#define RELUST16(h, B, a) \
  h[(B)+0]=fmaxf(a[0],0.f);    h[(B)+1]=fmaxf(a[1],0.f); \
  h[(B)+2]=fmaxf(a[2],0.f);    h[(B)+3]=fmaxf(a[3],0.f); \
  h[(B)+4]=fmaxf(a[4],0.f);    h[(B)+5]=fmaxf(a[5],0.f); \
  h[(B)+6]=fmaxf(a[6],0.f);    h[(B)+7]=fmaxf(a[7],0.f); \
  h[(B)+8]=fmaxf(a[8],0.f);    h[(B)+9]=fmaxf(a[9],0.f); \
  h[(B)+10]=fmaxf(a[10],0.f);  h[(B)+11]=fmaxf(a[11],0.f); \
  h[(B)+12]=fmaxf(a[12],0.f);  h[(B)+13]=fmaxf(a[13],0.f); \
  h[(B)+14]=fmaxf(a[14],0.f);  h[(B)+15]=fmaxf(a[15],0.f);

#define FOLD16(w) \
  ts0=fmaf(fmaxf(acc[0],0.f),(w)[0],ts0);   ts1=fmaf(fmaxf(acc[1],0.f),(w)[1],ts1); \
  ts0=fmaf(fmaxf(acc[2],0.f),(w)[2],ts0);   ts1=fmaf(fmaxf(acc[3],0.f),(w)[3],ts1); \
  ts0=fmaf(fmaxf(acc[4],0.f),(w)[4],ts0);   ts1=fmaf(fmaxf(acc[5],0.f),(w)[5],ts1); \
  ts0=fmaf(fmaxf(acc[6],0.f),(w)[6],ts0);   ts1=fmaf(fmaxf(acc[7],0.f),(w)[7],ts1); \
  ts0=fmaf(fmaxf(acc[8],0.f),(w)[8],ts0);   ts1=fmaf(fmaxf(acc[9],0.f),(w)[9],ts1); \
  ts0=fmaf(fmaxf(acc[10],0.f),(w)[10],ts0); ts1=fmaf(fmaxf(acc[11],0.f),(w)[11],ts1); \
  ts0=fmaf(fmaxf(acc[12],0.f),(w)[12],ts0); ts1=fmaf(fmaxf(acc[13],0.f),(w)[13],ts1); \
  ts0=fmaf(fmaxf(acc[14],0.f),(w)[14],ts0); ts1=fmaf(fmaxf(acc[15],0.f),(w)[15],ts1);

// 4 k-steps consuming one float4 of input; weights advance 64 floats/row.
#define L1CHUNK(xv) \
  { const float* w_=w1p;     FMA16(acc,(xv).x,w_) } \
  { const float* w_=w1p+64;  FMA16(acc,(xv).y,w_) } \
  { const float* w_=w1p+128; FMA16(acc,(xv).z,w_) } \
  { const float* w_=w1p+192; FMA16(acc,(xv).w,w_) }

// L2 k-step: h1[(k)] is a literal index; weights are wave-uniform reads
// (scalar-promotable) with compile-time offsets.
#define L2K(k)   { const float* w_=w2base+(k)*64; FMA16(acc, h1[(k)], w_) }
#define L2K4(k)  L2K(k) L2K((k)+1) L2K((k)+2) L2K((k)+3)
#define L2K16(k) L2K4(k) L2K4((k)+4) L2K4((k)+8) L2K4((k)+12)

// Shared L2 + folded L3 (64->64 relu -> dot w3), mb tiles of 16 rolled.
#define MLP_L2_FOLD(W2p, B2p, W3p) \
  _Pragma("unroll 1") \
  for (int mb = 0; mb < 4; ++mb) { \
      const float* w2base = (W2p) + mb*16; \
      float acc[16]; \
      LOAD16(acc, (B2p) + mb*16) \
      L2K16(0) L2K16(16) L2K16(32) L2K16(48) \
      const float* w3_ = (W3p) + mb*16; \
      FOLD16(w3_) \
  }

// ---------------- K1: jet MLP, lane = jet ----------------
__global__ __launch_bounds__(256, 1)
void jet_mlp_kernel(const float* __restrict__ jet_inp,
                    const float* __restrict__ jW1, const float* __restrict__ jb1,
                    const float* __restrict__ jW2, const float* __restrict__ jb2,
                    const float* __restrict__ jW3, const float* __restrict__ jb3,
                    float* __restrict__ ws, int B)
{
    const int jet = blockIdx.x * 256 + threadIdx.x;
    if (jet >= B) return;
    const float* jp = jet_inp + (size_t)jet * 16;

    float h1[64];
    // L1: 4 output-tiles of 16; x streamed as float4 chunks (L1/L2-cached).
#define L1TILE_K1(T) { \
    float acc[16]; \
    LOAD16(acc, jb1 + (T)*16) \
    const float* w1p = jW1 + (T)*16; \
    _Pragma("unroll 1") \
    for (int c = 0; c < 4; ++c) { \
        const float4 xv = *(const float4*)(jp + c*4); \
        L1CHUNK(xv) \
        w1p += 256; } \
    RELUST16(h1, (T)*16, acc) }
    L1TILE_K1(0) L1TILE_K1(1) L1TILE_K1(2) L1TILE_K1(3)
#undef L1TILE_K1

    float ts0 = 0.f, ts1 = 0.f;
    MLP_L2_FOLD(jW2, jb2, jW3)
    ws[jet] = sigmoid_fast(ts0 + ts1 + jb3[0]);
}

// ---------------- K2: neighbor streams, lane = (jet_half, neighbor) ----------------
__global__ __launch_bounds__(256, 1)
void neigh_streams_kernel(const float* __restrict__ jet_inp,
                          const float* __restrict__ neigh_inp,
                          const float* __restrict__ nW1, const float* __restrict__ nb1,
                          const float* __restrict__ nW2, const float* __restrict__ nb2,
                          const float* __restrict__ nW3, const float* __restrict__ nb3,
                          const float* __restrict__ jet_eff,
                          float* __restrict__ out, int B)
{
    const int lane = threadIdx.x & 63;
    const int half = lane >> 5;   // 0 = jet A, 1 = jet B
    const int nb   = lane & 31;   // neighbor index
    const int wid  = threadIdx.x >> 6;
    const int gw = blockIdx.x * 4 + wid;
    const int nw = gridDim.x * 4;
    const int npairs = B >> 1;
    const float bias3 = nb3[0];

    for (int pair = gw; pair < npairs; pair += nw) {
        const int jet = pair * 2 + half;
        const float* jp = jet_inp   + (size_t)jet * 16;
        const float* np = neigh_inp + (size_t)jet * (NNB*16) + (size_t)nb * 16;

        float h1[64];
        // L1: rows 0..15 = jet feats, rows 16..31 = neighbor feats (concat order).
#define L1TILE_K2(T) { \
        float acc[16]; \
        LOAD16(acc, nb1 + (T)*16) \
        const float* w1p = nW1 + (T)*16; \
        _Pragma("unroll 1") \
        for (int c = 0; c < 4; ++c) { \
            const float4 xv = *(const float4*)(jp + c*4); \
            L1CHUNK(xv) \
            w1p += 256; } \
        _Pragma("unroll 1") \
        for (int c = 0; c < 4; ++c) { \
            const float4 xv = *(const float4*)(np + c*4); \
            L1CHUNK(xv) \
            w1p += 256; } \
        RELUST16(h1, (T)*16, acc) }
        L1TILE_K2(0) L1TILE_K2(1) L1TILE_K2(2) L1TILE_K2(3)
#undef L1TILE_K2

        float ts0 = 0.f, ts1 = 0.f;
        MLP_L2_FOLD(nW2, nb2, nW3)
        const float t_n = ts0 + ts1 + bias3;

        // log-sigmoid, then 5-shuffle sum within each 32-lane half
        float ls = -__logf(1.0f + __expf(-t_n));
#pragma unroll
        for (int off = 16; off >= 1; off >>= 1)
            ls += __shfl_xor(ls, off, 64);
        const float corr = __expf(ls);

        if (nb == 0) out[jet] = jet_eff[jet] * corr;
    }
}

extern "C" void kernel_launch(void* const* d_in, const int* in_sizes, int n_in,
                              void* d_out, int out_size, void* d_ws, size_t ws_size,
                              hipStream_t stream) {
    const float* jet_inp = (const float*)d_in[0];
    const float* neigh   = (const float*)d_in[1];
    const float* jW1 = (const float*)d_in[2];
    const float* jb1 = (const float*)d_in[3];
    const float* jW2 = (const float*)d_in[4];
    const float* jb2 = (const float*)d_in[5];
    const float* jW3 = (const float*)d_in[6];
    const float* jb3 = (const float*)d_in[7];
    const float* nW1 = (const float*)d_in[8];
    const float* nb1 = (const float*)d_in[9];
    const float* nW2 = (const float*)d_in[10];
    const float* nb2 = (const float*)d_in[11];
    const float* nW3 = (const float*)d_in[12];
    const float* nb3 = (const float*)d_in[13];
    float* out = (float*)d_out;
    float* ws  = (float*)d_ws;
    const int B = in_sizes[0] / 16;

    hipLaunchKernelGGL(jet_mlp_kernel, dim3((B + 255) / 256), dim3(256), 0, stream,
                       jet_inp, jW1, jb1, jW2, jb2, jW3, jb3, ws, B);
    hipLaunchKernelGGL(neigh_streams_kernel, dim3(2048), dim3(256), 0, stream,
                       jet_inp, neigh, nW1, nb1, nW2, nb2, nW3, nb3,
                       ws, out, B);
}